// Round 10
// baseline (3206.324 us; speedup 1.0000x reference)
//
#include <hip/hip_runtime.h>
#include <hip/hip_bf16.h>
#include <math.h>

typedef __hip_bfloat16 bf16;
typedef unsigned long long u64;
typedef unsigned int u32;

#define LTT 4
#define DIM 256
#define NTOK 32768      // total tokens (4*8*1024)
#define MT 2097152      // elements per time step (8192 tokens * 256)
#define NTOT 8388608

// dual-dtype load with finite clamp: f=1 -> fp32, f=0 -> bf16
__device__ __forceinline__ float ldin(const void* p, size_t i, int f) {
  float v = f ? ((const float*)p)[i] : __bfloat162float(((const bf16*)p)[i]);
  return isfinite(v) ? v : 0.0f;
}

// ---------------- per-input dtype probe ----------------
// fp32 if: any bf16-exponent >= 0xC0 in first min(n,1024) halfwords (random
// fp32 mantissa halves trigger; |bf16| >= 2^65 never occurs here), OR
// halfword0 == 0 while buffer is nonzero / single-element (fp32 ones, 0.5).
// All-zero buffers -> flag 0 (zeros read correctly either way).
__global__ void probe1_k(const void* p, int nelem, int* flag) {
  int tid = threadIdx.x;  // 64
  const unsigned short* u = (const unsigned short*)p;
  int n = nelem < 1024 ? nelem : 1024;
  bool big = false, nz = false;
  for (int i = tid; i < n; i += 64) {
    unsigned short h = u[i];
    if (((h >> 7) & 0xFF) >= 0xC0) big = true;
    if (h != 0) nz = true;
  }
  u64 bm = __ballot(big);
  u64 zm = __ballot(nz);
  if (tid == 0) {
    unsigned short h0 = u[0];
    int f = 0;
    if (bm != 0ull) f = 1;
    else if (h0 == 0 && (zm != 0ull || n == 1)) f = 1;
    *flag = f;
  }
}

__global__ void setone_k(int* p) { *p = 1; }

// ---------------- batchnorm stats: per-channel sums over 32768 tokens ----------------
__global__ void bnstats_k(const void* __restrict__ x, const int* __restrict__ fxp,
                          float* __restrict__ gsum, float* __restrict__ gsq) {
  int fx = *fxp;
  int c = threadIdx.x;            // 256 channels
  int tok0 = blockIdx.x * 128;    // 256 blocks * 128 tokens
  float s = 0.f, q = 0.f;
  for (int t = 0; t < 128; t++) {
    float v = ldin(x, (size_t)(tok0 + t) * DIM + c, fx);
    s += v; q += v * v;
  }
  atomicAdd(&gsum[c], s);
  atomicAdd(&gsq[c], q);
}

// ---------------- fused BN-apply + LIF scan over t; spikes bit-packed ----------------
__global__ void lif_k(const void* __restrict__ x, const int* __restrict__ fxp,
                      const float* __restrict__ gsum, const float* __restrict__ gsq,
                      const void* __restrict__ gamma, const int* __restrict__ fgp,
                      const void* __restrict__ beta, const int* __restrict__ fbp,
                      u64* __restrict__ bits) {
  int fx = *fxp, fg = *fgp, fb = *fbp;
  int m = blockIdx.x * 256 + threadIdx.x;   // [0, MT)
  int c = m & (DIM - 1);
  int lane = threadIdx.x & 63;
  float mean = gsum[c] * (1.0f / 32768.0f);
  float var  = gsq[c] * (1.0f / 32768.0f) - mean * mean;
  float inv  = rsqrtf(var + 1e-5f);
  float g = ldin(gamma, c, fg), be = ldin(beta, c, fb);
  float v = 0.f;
  #pragma unroll
  for (int t = 0; t < LTT; t++) {
    size_t e = (size_t)t * MT + m;
    float xn = (ldin(x, e, fx) - mean) * inv * g + be;
    v = v + (xn - v) * 0.5f;                 // TAU = 2
    bool sp = (v - 1.0f >= 0.0f);            // VTH = 1
    u64 bl = __ballot(sp);
    if (lane == 0) bits[e >> 6] = bl;        // e>>6 is wave-uniform
    v = sp ? 0.0f : v;
  }
}

// ---------------- generic 64x64-tile GEMM, fp32 accum ----------------
// A: AF=0 internal bf16, AF=2 bit-packed spikes. B/bias: flag-dispatched inputs.
// MODE 2: O(bf16) = gelu(acc+bias)                     (FFN hidden, obase=0)
// MODE 3: O(bf16) = acc+bias                           (qkv, obase=0)
// MODE 4: Of32[obase+o] = xin[obase+o] + scl*(acc+bias)  -- d_out is FP32
//         (reference output dtype). FFN2 aliases O==xin (same element, same
//         thread) -> O/xinv deliberately NOT __restrict__.
__device__ __forceinline__ float gelu_f(float x) {
  return 0.5f * x * (1.0f + erff(x * 0.70710678118654752440f));
}

template <int MODE, int AF>
__global__ void __launch_bounds__(256)
gemm_k(const void* __restrict__ Av,
       const void* __restrict__ Bv, const int* __restrict__ fBp,
       const void* __restrict__ biasv, const int* __restrict__ fbp,
       void* O, const void* xinv, const int* __restrict__ fxp,
       const void* __restrict__ scalev, const int* __restrict__ fsp,
       int N, int K, size_t obase) {
  int fB = *fBp, fbias = *fbp;
  const bf16* Ab = (const bf16*)Av;
  const u32* Abits = (const u32*)Av;
  __shared__ __align__(16) float Ast[16][68];   // [k][m], padded
  __shared__ __align__(16) float Bs[16][68];    // [k][n], padded
  int tid = threadIdx.x;
  int bm = blockIdx.y * 64, bn = blockIdx.x * 64;
  int tr = tid >> 4, tc = tid & 15;
  float acc[4][4] = {};
  for (int k0 = 0; k0 < K; k0 += 16) {
    for (int t = tid; t < 1024; t += 256) {
      int m = t >> 4, k = t & 15;
      float av;
      if (AF == 2) {
        int kg = k0 + k;
        u32 w = Abits[(size_t)(bm + m) * (K >> 5) + (kg >> 5)];
        av = (float)((w >> (kg & 31)) & 1u);
      } else {
        av = __bfloat162float(Ab[(size_t)(bm + m) * K + k0 + k]);
      }
      Ast[k][m] = av;
    }
    for (int t = tid; t < 1024; t += 256) {
      int k = t >> 6, n = t & 63;
      Bs[k][n] = ldin(Bv, (size_t)(k0 + k) * N + bn + n, fB);
    }
    __syncthreads();
    #pragma unroll
    for (int kk = 0; kk < 16; kk++) {
      float4 a4 = *(const float4*)&Ast[kk][tr * 4];
      float4 b4 = *(const float4*)&Bs[kk][tc * 4];
      float a[4] = {a4.x, a4.y, a4.z, a4.w};
      float b[4] = {b4.x, b4.y, b4.z, b4.w};
      #pragma unroll
      for (int i = 0; i < 4; i++)
        #pragma unroll
        for (int jj = 0; jj < 4; jj++)
          acc[i][jj] += a[i] * b[jj];
    }
    __syncthreads();
  }
  float scl = 0.f;
  int fx = 0;
  if (MODE == 4) { scl = ldin(scalev, 0, *fsp); fx = *fxp; }
  #pragma unroll
  for (int i = 0; i < 4; i++) {
    int m = bm + tr * 4 + i;
    #pragma unroll
    for (int jj = 0; jj < 4; jj++) {
      int n = bn + tc * 4 + jj;
      float v = acc[i][jj] + ldin(biasv, n, fbias);
      size_t o = obase + (size_t)m * N + n;
      if (MODE == 2) {
        ((bf16*)O)[o] = __float2bfloat16(gelu_f(v));
      } else if (MODE == 3) {
        ((bf16*)O)[o] = __float2bfloat16(v);
      } else {  // MODE 4: fp32 store; same-element read-before-write per thread
        float base = ldin(xinv, o, fx);
        ((float*)O)[o] = base + scl * v;
      }
    }
  }
}

// ---------------- region-mean of s1 bits + qr/kr projection ----------------
__global__ void srqkr_k(const u64* __restrict__ bits,
                        const void* __restrict__ Wqkv, const int* __restrict__ fWp,
                        const void* __restrict__ bqkv, const int* __restrict__ fbp,
                        float* __restrict__ qr, float* __restrict__ kr) {
  int fW = *fWp, fb = *fbp;
  int blk = blockIdx.x;   // (t*8+b)*16 + r, 512 regions
  int c = threadIdx.x;    // 256
  __shared__ float s_s[256];
  float s = 0.f;
  for (int i = 0; i < 64; i++) {
    int g = blk * 64 + i;                       // global token
    u64 w = bits[(size_t)g * 4 + (c >> 6)];
    s += (float)((w >> (c & 63)) & 1ull);
  }
  s_s[c] = s * (1.0f / 64.0f);
  __syncthreads();
  float aq = 0.f, ak = 0.f;
  for (int k = 0; k < 256; k++) {
    float sv = s_s[k];
    aq += sv * ldin(Wqkv, (size_t)k * 768 + c, fW);
    ak += sv * ldin(Wqkv, (size_t)k * 768 + 256 + c, fW);
  }
  qr[(size_t)blk * DIM + c] = aq + ldin(bqkv, c, fb);
  kr[(size_t)blk * DIM + c] = ak + ldin(bqkv, 256 + c, fb);
}

// ---------------- affinity + top-4 (ties -> lowest index, matches lax.top_k) ----------------
__global__ void afftopk_k(const float* __restrict__ qr, const float* __restrict__ kr,
                          int* __restrict__ idx) {
  int blk = blockIdx.x;       // (t*8+b)*16 + r
  int tb = blk >> 4;
  int tid = threadIdx.x;      // 256
  int s_ = tid >> 4, p = tid & 15;
  __shared__ float part[256];
  __shared__ float aff[16];
  const float* qrow = qr + (size_t)blk * 256;
  const float* krow = kr + (size_t)(tb * 16 + s_) * 256;
  float acc = 0.f;
  for (int c = p * 16; c < p * 16 + 16; c++) acc += qrow[c] * krow[c];
  part[tid] = acc;
  __syncthreads();
  if (tid < 16) {
    float a = 0.f;
    for (int pp = 0; pp < 16; pp++) a += part[tid * 16 + pp];
    aff[tid] = a;
  }
  __syncthreads();
  if (tid == 0) {
    bool taken[16] = {};
    for (int kk = 0; kk < 4; kk++) {
      float best = -INFINITY; int bi = 0;
      for (int i = 0; i < 16; i++)
        if (!taken[i] && aff[i] > best) { best = aff[i]; bi = i; }
      taken[bi] = true;
      idx[blk * 4 + kk] = bi;
    }
  }
}

// ---------------- gathered attention per (b_local, r, h) within a chunk ----------------
__global__ void __launch_bounds__(256)
attn_k(const bf16* __restrict__ qkv, const int* __restrict__ idx,
       bf16* __restrict__ ctx) {
  __shared__ __align__(16) float qs[64 * 32];     // 8 KB
  __shared__ __align__(16) float sc[256 * 36];    // 36 KB (half the i-rows at a time)
  __shared__ int ridxs[4];
  int blk = blockIdx.x;             // (b_local*16+r)*8 + h
  int h = blk & 7, br = blk >> 3;
  int b = br >> 4;                  // chunk-local batch
  int tid = threadIdx.x;
  if (tid < 4) ridxs[tid] = idx[br * 4 + tid];
  int base = br * 64;               // chunk-local token base
  for (int e = tid; e < 2048; e += 256) {
    int i = e >> 5, d = e & 31;
    qs[i * 32 + d] = __bfloat162float(qkv[(size_t)(base + i) * 768 + h * 32 + d]);
  }
  __syncthreads();

  int j = tid;
  int ktok = b * 1024 + ridxs[j >> 6] * 64 + (j & 63);
  const bf16* krow = qkv + (size_t)ktok * 768 + 256 + h * 32;
  float kreg[32];
  #pragma unroll
  for (int d2 = 0; d2 < 32; d2++) kreg[d2] = __bfloat162float(krow[d2]);

  int d = tid & 31, ig = tid >> 5;
  for (int half = 0; half < 2; half++) {
    for (int i2 = 0; i2 < 32; i2++) {
      int i = half * 32 + i2;
      const float4* q4p = (const float4*)&qs[i * 32];
      float acc = 0.f;
      #pragma unroll
      for (int q4 = 0; q4 < 8; q4++) {
        float4 ff = q4p[q4];
        acc += ff.x * kreg[4*q4] + ff.y * kreg[4*q4+1] + ff.z * kreg[4*q4+2] + ff.w * kreg[4*q4+3];
      }
      sc[j * 36 + i2] = acc * 0.17677669529663687f;   // 1/sqrt(32)
    }
    __syncthreads();
    if (tid < 32) {                                   // serial softmax per query row
      int i2 = tid;
      float mx = -INFINITY;
      for (int jj = 0; jj < 256; jj++) mx = fmaxf(mx, sc[jj * 36 + i2]);
      float sum = 0.f;
      for (int jj = 0; jj < 256; jj++) {
        float e = expf(sc[jj * 36 + i2] - mx);
        sc[jj * 36 + i2] = e; sum += e;
      }
      float inv = 1.0f / sum;
      for (int jj = 0; jj < 256; jj++) sc[jj * 36 + i2] *= inv;
    }
    __syncthreads();
    float acc4[4] = {0.f, 0.f, 0.f, 0.f};
    for (int jj = 0; jj < 256; jj++) {
      int vt = b * 1024 + ridxs[jj >> 6] * 64 + (jj & 63);
      float vv = __bfloat162float(qkv[(size_t)vt * 768 + 512 + h * 32 + d]);
      float4 p4 = *(const float4*)&sc[jj * 36 + ig * 4];
      acc4[0] += p4.x * vv; acc4[1] += p4.y * vv;
      acc4[2] += p4.z * vv; acc4[3] += p4.w * vv;
    }
    #pragma unroll
    for (int ii = 0; ii < 4; ii++) {
      int i = half * 32 + ig * 4 + ii;
      ctx[(size_t)(base + i) * 256 + h * 32 + d] = __float2bfloat16(acc4[ii]);
    }
    __syncthreads();
  }
}

// ---------------- launch ----------------
extern "C" void kernel_launch(void* const* d_in, const int* in_sizes, int n_in,
                              void* d_out, int out_size, void* d_ws, size_t ws_size,
                              hipStream_t stream) {
  const void* x_in = d_in[0];
  const void* Wqkv = d_in[3];
  const void* bqkv = d_in[4];
  const void* Wo   = d_in[5];
  const void* bo   = d_in[6];
  const void* W1   = d_in[9];
  const void* b1   = d_in[10];
  const void* W2   = d_in[11];
  const void* b2   = d_in[12];
  const void* scale = d_in[13];

  // misc: flags(256B) + qr/kr(1MB) + idx(8KB) + bits(1MB) + gsum/gsq(2KB)
  const size_t MISC = 256 + 2 * 524288 + 8192 + 1048576 + 2048;
  int bcq, TC;
  if (MISC + 8388608 <= ws_size) { bcq = 4; TC = 4096; }   // ~10.5 MB
  else                           { bcq = 1; TC = 1024; }   // ~4.2 MB
  size_t r0 = (size_t)bcq * 2097152;   // qkvb (bcq*1.5MB) + ctxb (bcq*0.5MB)
  { size_t hb = (size_t)TC * 2048; if (hb > r0) r0 = hb; }

  char* ws = (char*)d_ws;
  int*  flags = (int*)ws;      // [0..13] per-input dtype; [14]=0 (bf16); [15]=1 (fp32)
  char* p = ws + 256;
  bf16* qkvb = (bf16*)p;
  bf16* ctxb = (bf16*)(p + (size_t)bcq * 1572864);
  bf16* hbuf = (bf16*)p;               // aliases qkvb/ctxb (disjoint phases)
  p += r0;
  float* qr   = (float*)p;  p += 524288;
  float* kr   = (float*)p;  p += 524288;
  int*   idxb = (int*)p;    p += 8192;
  u64*   bits = (u64*)p;    p += 1048576;   // s1 bits, later s2 bits
  float* gsum = (float*)p;  p += 2048;
  float* gsq  = gsum + 256;
  float* out  = (float*)d_out;         // FP32 output: x_mid, then final (in place)
  const int* F14 = flags + 14;         // const bf16 flag (0)
  const int* F15 = flags + 15;         // const fp32 flag (1)

  // ---- dtype probes ----
  hipMemsetAsync(flags, 0, 256, stream);
  setone_k<<<1, 1, 0, stream>>>(flags + 15);
  for (int i = 0; i < 14; i++)
    probe1_k<<<1, 64, 0, stream>>>(d_in[i], in_sizes[i], flags + i);

  // ---- block 1: BN1 + LIF -> s1 bits ----
  hipMemsetAsync(gsum, 0, 512 * sizeof(float), stream);
  bnstats_k<<<256, 256, 0, stream>>>(x_in, flags + 0, gsum, gsq);
  lif_k<<<MT / 256, 256, 0, stream>>>(x_in, flags + 0, gsum, gsq,
                                      d_in[1], flags + 1, d_in[2], flags + 2, bits);

  // ---- region routing ----
  srqkr_k<<<512, 256, 0, stream>>>(bits, Wqkv, flags + 3, bqkv, flags + 4, qr, kr);
  afftopk_k<<<512, 256, 0, stream>>>(qr, kr, idxb);

  // ---- attention chunks: s1 bits -> qkv -> attn -> x_mid = x + scale*(ctx@Wo+bo) ----
  for (int t = 0; t < LTT; t++) {
    for (int b0 = 0; b0 < 8; b0 += bcq) {
      size_t tok0 = ((size_t)t * 8 + b0) * 1024;
      gemm_k<3, 2><<<dim3(12, bcq * 16), 256, 0, stream>>>(
          (const void*)((const u32*)bits + tok0 * 8), Wqkv, flags + 3,
          bqkv, flags + 4, qkvb, nullptr, F14, nullptr, F14, 768, 256, 0);
      attn_k<<<bcq * 128, 256, 0, stream>>>(qkvb, idxb + (t * 8 + b0) * 64, ctxb);
      gemm_k<4, 0><<<dim3(4, bcq * 16), 256, 0, stream>>>(
          ctxb, Wo, flags + 5, bo, flags + 6, out, x_in, flags + 0,
          scale, flags + 13, 256, 256, tok0 * 256);
    }
  }

  // ---- block 2: BN2 + LIF on x_mid (fp32, in d_out) -> s2 bits ----
  hipMemsetAsync(gsum, 0, 512 * sizeof(float), stream);
  bnstats_k<<<256, 256, 0, stream>>>(out, F15, gsum, gsq);
  lif_k<<<MT / 256, 256, 0, stream>>>(out, F15, gsum, gsq,
                                      d_in[7], flags + 7, d_in[8], flags + 8, bits);

  // ---- FFN chunks: s2 bits -> gelu hidden -> out = x_mid + scale*(h@W2+b2) in place ----
  for (int c = 0; c * TC < NTOK; c++) {
    size_t tok0 = (size_t)c * TC;
    gemm_k<2, 2><<<dim3(16, TC / 64), 256, 0, stream>>>(
        (const void*)((const u32*)bits + tok0 * 8), W1, flags + 9,
        b1, flags + 10, hbuf, nullptr, F14, nullptr, F14, 1024, 256, 0);
    gemm_k<4, 0><<<dim3(4, TC / 64), 256, 0, stream>>>(
        hbuf, W2, flags + 11, b2, flags + 12, out, out, F15,
        scale, flags + 13, 256, 1024, tok0 * 256);
  }
}